// Round 2
// baseline (177.987 us; speedup 1.0000x reference)
//
#include <hip/hip_runtime.h>
#include <math.h>

#define B 32
#define S 8
#define FEA 2560
#define T 800
#define TV 200   // T/4 float4 count
#define NCL 512
#define EMB 256
#define H 8

__device__ __forceinline__ float dot4(float4 a, float4 b) {
    return a.x * b.x + a.y * b.y + a.z * b.z + a.w * b.w;
}

// ---------------- Kernel 1: pooled[b,s,f] = sum_t x[b,f,t]*mask[b,s,t] ----------------
// grid (FEA/16 = 160, B), block 256 (4 waves, 4 features per wave).
// mask[b,:,:] staged in LDS; x loads batched 8-deep for latency hiding.
__global__ __launch_bounds__(256) void pool_kernel(const float4* __restrict__ x4,
                                                   const float4* __restrict__ mask4,
                                                   float* __restrict__ pooled) {
    __shared__ float4 mlds[S * TV];   // 25.6 KB
    const int b   = blockIdx.y;
    const int tid = threadIdx.x;
    for (int i = tid; i < S * TV; i += 256) mlds[i] = mask4[b * S * TV + i];
    __syncthreads();

    const int wave = tid >> 6, lane = tid & 63;
    const int f0 = blockIdx.x * 16 + wave * 4;
    const float4* xb = x4 + (size_t)b * FEA * TV;

    float acc[4][8];
    #pragma unroll
    for (int ff = 0; ff < 4; ++ff)
        #pragma unroll
        for (int s = 0; s < 8; ++s) acc[ff][s] = 0.f;

    // ---- batch 1: t-chunks 0,1 (always in range) ----
    {
        float4 xv[8];
        #pragma unroll
        for (int ic = 0; ic < 2; ++ic) {
            const int tv = ic * 64 + lane;
            #pragma unroll
            for (int ff = 0; ff < 4; ++ff)
                xv[ic * 4 + ff] = xb[(size_t)(f0 + ff) * TV + tv];
        }
        #pragma unroll
        for (int ic = 0; ic < 2; ++ic) {
            const int tv = ic * 64 + lane;
            float4 mk[8];
            #pragma unroll
            for (int s = 0; s < 8; ++s) mk[s] = mlds[s * TV + tv];
            #pragma unroll
            for (int ff = 0; ff < 4; ++ff)
                #pragma unroll
                for (int s = 0; s < 8; ++s)
                    acc[ff][s] += dot4(xv[ic * 4 + ff], mk[s]);
        }
    }
    // ---- batch 2: t-chunks 2,3 (chunk 3 partial: tv=192+lane valid iff lane<8) ----
    {
        const float4 z = make_float4(0.f, 0.f, 0.f, 0.f);
        float4 xv[8];
        #pragma unroll
        for (int ic = 0; ic < 2; ++ic) {
            const int tv = (ic + 2) * 64 + lane;
            #pragma unroll
            for (int ff = 0; ff < 4; ++ff)
                xv[ic * 4 + ff] = (tv < TV) ? xb[(size_t)(f0 + ff) * TV + tv] : z;
        }
        #pragma unroll
        for (int ic = 0; ic < 2; ++ic) {
            const int tv = (ic + 2) * 64 + lane;
            const int tvc = (tv < TV) ? tv : 0;   // clamp: xv already zeroed, avoid NaN*0
            float4 mk[8];
            #pragma unroll
            for (int s = 0; s < 8; ++s) mk[s] = mlds[s * TV + tvc];
            #pragma unroll
            for (int ff = 0; ff < 4; ++ff)
                #pragma unroll
                for (int s = 0; s < 8; ++s)
                    acc[ff][s] += dot4(xv[ic * 4 + ff], mk[s]);
        }
    }

    // cross-lane t-reduction + single-lane scattered stores
    #pragma unroll
    for (int ff = 0; ff < 4; ++ff)
        #pragma unroll
        for (int s = 0; s < 8; ++s) {
            float v = acc[ff][s];
            #pragma unroll
            for (int off = 32; off > 0; off >>= 1) v += __shfl_xor(v, off, 64);
            if (lane == ff * 8 + s) pooled[((b * S + s) * FEA) + f0 + ff] = v;
        }
}

// ---------------- Kernel 2: w[b,s,h] and u[n,h] ----------------
__global__ __launch_bounds__(256) void wu_kernel(const float* __restrict__ pooled,
                                                 const float* __restrict__ mask,
                                                 const float* __restrict__ W_w,
                                                 const float* __restrict__ W_b,
                                                 const float* __restrict__ U_w,
                                                 const float* __restrict__ U_b,
                                                 const float* __restrict__ m,
                                                 float* __restrict__ w_out,
                                                 float* __restrict__ u_out) {
    const int blk = blockIdx.x;
    const int tid = threadIdx.x;

    if (blk >= B * S) {
        // ---- u blocks ----
        const int base = (blk - B * S) * 64;
        const int n  = base + (tid >> 2);
        const int h0 = (tid & 3) * 2;
        float a0 = 0.f, a1 = 0.f;
        for (int e = 0; e < EMB; ++e) {
            const float mv = m[n * EMB + e];
            a0 += mv * U_w[h0 * EMB + e];
            a1 += mv * U_w[(h0 + 1) * EMB + e];
        }
        u_out[n * H + h0]     = a0 + U_b[h0];
        u_out[n * H + h0 + 1] = a1 + U_b[h0 + 1];
        return;
    }

    const int b = blk >> 3, s = blk & 7;
    __shared__ float red[256];
    __shared__ float wred[4][8];

    float p = 0.f;
    for (int t = tid; t < T; t += 256) p += mask[(b * S + s) * T + t];
    red[tid] = p;
    __syncthreads();
    for (int st = 128; st > 0; st >>= 1) {
        if (tid < st) red[tid] += red[tid + st];
        __syncthreads();
    }
    const float inv_d = 1.f / (red[0] + 1e-10f);

    float acc[8];
    #pragma unroll
    for (int h = 0; h < 8; ++h) acc[h] = 0.f;
    for (int f = tid; f < FEA; f += 256) {
        const float xv = pooled[(b * S + s) * FEA + f] * inv_d;
        #pragma unroll
        for (int h = 0; h < 8; ++h) acc[h] += xv * W_w[h * FEA + f];
    }
    const int lane = tid & 63, wave = tid >> 6;
    #pragma unroll
    for (int h = 0; h < 8; ++h) {
        float v = acc[h];
        #pragma unroll
        for (int off = 32; off > 0; off >>= 1) v += __shfl_xor(v, off, 64);
        if (lane == 0) wred[wave][h] = v;
    }
    __syncthreads();
    if (tid < 8) {
        const float v = wred[0][tid] + wred[1][tid] + wred[2][tid] + wred[3][tid] + W_b[tid];
        w_out[(b * S + s) * H + tid] = v;
    }
}

// ---------------- Kernel 3: gate + e = a @ m ----------------
__global__ __launch_bounds__(256) void attn_kernel(const float* __restrict__ w_in,
                                                   const float* __restrict__ u_in,
                                                   const float* __restrict__ v_w,
                                                   const float* __restrict__ v_b,
                                                   const float* __restrict__ m,
                                                   float* __restrict__ out) {
    __shared__ float u_lds[NCL * H];   // 16 KB
    __shared__ float a_lds[NCL];
    __shared__ float w_sh[H];
    const int bs  = blockIdx.x;
    const int tid = threadIdx.x;

    for (int i = tid; i < NCL * H; i += 256) u_lds[i] = u_in[i];
    if (tid < H) w_sh[tid] = w_in[bs * H + tid];
    __syncthreads();

    float vw[8];
    #pragma unroll
    for (int h = 0; h < 8; ++h) vw[h] = v_w[h];
    const float vb = v_b[0];

    for (int n = tid; n < NCL; n += 256) {
        float c = vb;
        #pragma unroll
        for (int h = 0; h < 8; ++h) c += tanhf(w_sh[h] + u_lds[n * H + h]) * vw[h];
        a_lds[n] = 1.f / (1.f + expf(-c));
    }
    __syncthreads();

    float acc = 0.f;
    #pragma unroll 4
    for (int n = 0; n < NCL; ++n) acc += a_lds[n] * m[n * EMB + tid];
    out[bs * EMB + tid] = acc;
}

extern "C" void kernel_launch(void* const* d_in, const int* in_sizes, int n_in,
                              void* d_out, int out_size, void* d_ws, size_t ws_size,
                              hipStream_t stream) {
    const float* x    = (const float*)d_in[0];
    const float* mask = (const float*)d_in[1];
    const float* W_w  = (const float*)d_in[2];
    const float* W_b  = (const float*)d_in[3];
    const float* U_w  = (const float*)d_in[4];
    const float* U_b  = (const float*)d_in[5];
    const float* v_w  = (const float*)d_in[6];
    const float* v_b  = (const float*)d_in[7];
    const float* m    = (const float*)d_in[8];
    float* out = (float*)d_out;

    float* ws     = (float*)d_ws;
    float* pooled = ws;                       // B*S*FEA floats
    float* w_buf  = ws + B * S * FEA;
    float* u_buf  = w_buf + B * S * H;

    pool_kernel<<<dim3(FEA / 16, B), 256, 0, stream>>>(
        (const float4*)x, (const float4*)mask, pooled);
    wu_kernel<<<B * S + NCL / 64, 256, 0, stream>>>(
        pooled, mask, W_w, W_b, U_w, U_b, m, w_buf, u_buf);
    attn_kernel<<<B * S, 256, 0, stream>>>(w_buf, u_buf, v_w, v_b, m, out);
}

// Round 3
// 118.032 us; speedup vs baseline: 1.5080x; 1.5080x over previous
//
#include <hip/hip_runtime.h>
#include <hip/hip_bf16.h>
#include <math.h>

#define B 32
#define S 8
#define FEA 2560
#define T 800
#define NCL 512
#define EMB 256
#define H 8

typedef __attribute__((ext_vector_type(8))) short bf16x8;
typedef __attribute__((ext_vector_type(4))) float f32x4;

// ---------------- Kernel 1: pooled[b,s,f] = sum_t x[b,f,t]*mask[b,s,t] via MFMA ----------------
// C(16x16) = A(mask, 16x32-slice) * B(x^T, 32x16-slice), K=T=800 in 25 steps.
// Rows 0..7 of A are the 8 speakers; rows 8..15 duplicate them and are ignored on store.
// One wave per 16-feature tile, full K. No LDS, no barriers, no shuffles.
__global__ __launch_bounds__(256) void pool_mfma_kernel(const float* __restrict__ x,
                                                        const float* __restrict__ mask,
                                                        float* __restrict__ pooled) {
    const int b    = blockIdx.y;
    const int wave = threadIdx.x >> 6;
    const int lane = threadIdx.x & 63;
    const int f0   = (blockIdx.x * 4 + wave) * 16;   // feature tile base

    const int row = lane & 15;   // A-row (speaker, mod 8) / B-col (feature)
    const int kb  = lane >> 4;   // k-block 0..3 (8 elements each)
    const int s   = row & 7;

    const float* xrow = x    + ((size_t)b * FEA + (size_t)(f0 + row)) * T + kb * 8;
    const float* mrow = mask + ((size_t)(b * S + s)) * T + kb * 8;

    f32x4 acc = {0.f, 0.f, 0.f, 0.f};

    #pragma unroll 5
    for (int k0 = 0; k0 < T; k0 += 32) {
        const float4 a0 = *(const float4*)(mrow + k0);
        const float4 a1 = *(const float4*)(mrow + k0 + 4);
        const float4 b0 = *(const float4*)(xrow + k0);
        const float4 b1 = *(const float4*)(xrow + k0 + 4);

        union { bf16x8 v; __hip_bfloat162 h[4]; } A, Bv;
        A.h[0]  = __float22bfloat162_rn(make_float2(a0.x, a0.y));
        A.h[1]  = __float22bfloat162_rn(make_float2(a0.z, a0.w));
        A.h[2]  = __float22bfloat162_rn(make_float2(a1.x, a1.y));
        A.h[3]  = __float22bfloat162_rn(make_float2(a1.z, a1.w));
        Bv.h[0] = __float22bfloat162_rn(make_float2(b0.x, b0.y));
        Bv.h[1] = __float22bfloat162_rn(make_float2(b0.z, b0.w));
        Bv.h[2] = __float22bfloat162_rn(make_float2(b1.x, b1.y));
        Bv.h[3] = __float22bfloat162_rn(make_float2(b1.z, b1.w));

        acc = __builtin_amdgcn_mfma_f32_16x16x32_bf16(A.v, Bv.v, acc, 0, 0, 0);
    }

    // C/D layout (m89-verified): col = lane&15, row = (lane>>4)*4 + i.
    // Rows 0..7 are real speakers -> lanes 0..31 store.
    if (lane < 32) {
        #pragma unroll
        for (int i = 0; i < 4; ++i) {
            const int srow = (lane >> 4) * 4 + i;
            pooled[(size_t)(b * S + srow) * FEA + f0 + row] = acc[i];
        }
    }
}

// ---------------- Kernel 2: w[b,s,h] and u[n,h] ----------------
__global__ __launch_bounds__(256) void wu_kernel(const float* __restrict__ pooled,
                                                 const float* __restrict__ mask,
                                                 const float* __restrict__ W_w,
                                                 const float* __restrict__ W_b,
                                                 const float* __restrict__ U_w,
                                                 const float* __restrict__ U_b,
                                                 const float* __restrict__ m,
                                                 float* __restrict__ w_out,
                                                 float* __restrict__ u_out) {
    const int blk = blockIdx.x;
    const int tid = threadIdx.x;

    if (blk >= B * S) {
        // ---- u blocks ----
        const int base = (blk - B * S) * 64;
        const int n  = base + (tid >> 2);
        const int h0 = (tid & 3) * 2;
        float a0 = 0.f, a1 = 0.f;
        for (int e = 0; e < EMB; ++e) {
            const float mv = m[n * EMB + e];
            a0 += mv * U_w[h0 * EMB + e];
            a1 += mv * U_w[(h0 + 1) * EMB + e];
        }
        u_out[n * H + h0]     = a0 + U_b[h0];
        u_out[n * H + h0 + 1] = a1 + U_b[h0 + 1];
        return;
    }

    const int b = blk >> 3, s = blk & 7;
    __shared__ float red[256];
    __shared__ float wred[4][8];

    float p = 0.f;
    for (int t = tid; t < T; t += 256) p += mask[(b * S + s) * T + t];
    red[tid] = p;
    __syncthreads();
    for (int st = 128; st > 0; st >>= 1) {
        if (tid < st) red[tid] += red[tid + st];
        __syncthreads();
    }
    const float inv_d = 1.f / (red[0] + 1e-10f);

    float acc[8];
    #pragma unroll
    for (int h = 0; h < 8; ++h) acc[h] = 0.f;
    for (int f = tid; f < FEA; f += 256) {
        const float xv = pooled[(b * S + s) * FEA + f] * inv_d;
        #pragma unroll
        for (int h = 0; h < 8; ++h) acc[h] += xv * W_w[h * FEA + f];
    }
    const int lane = tid & 63, wave = tid >> 6;
    #pragma unroll
    for (int h = 0; h < 8; ++h) {
        float v = acc[h];
        #pragma unroll
        for (int off = 32; off > 0; off >>= 1) v += __shfl_xor(v, off, 64);
        if (lane == 0) wred[wave][h] = v;
    }
    __syncthreads();
    if (tid < 8) {
        const float v = wred[0][tid] + wred[1][tid] + wred[2][tid] + wred[3][tid] + W_b[tid];
        w_out[(b * S + s) * H + tid] = v;
    }
}

// ---------------- Kernel 3: gate + e = a @ m ----------------
__global__ __launch_bounds__(256) void attn_kernel(const float* __restrict__ w_in,
                                                   const float* __restrict__ u_in,
                                                   const float* __restrict__ v_w,
                                                   const float* __restrict__ v_b,
                                                   const float* __restrict__ m,
                                                   float* __restrict__ out) {
    __shared__ float u_lds[NCL * H];   // 16 KB
    __shared__ float a_lds[NCL];
    __shared__ float w_sh[H];
    const int bs  = blockIdx.x;
    const int tid = threadIdx.x;

    for (int i = tid; i < NCL * H; i += 256) u_lds[i] = u_in[i];
    if (tid < H) w_sh[tid] = w_in[bs * H + tid];
    __syncthreads();

    float vw[8];
    #pragma unroll
    for (int h = 0; h < 8; ++h) vw[h] = v_w[h];
    const float vb = v_b[0];

    for (int n = tid; n < NCL; n += 256) {
        float c = vb;
        #pragma unroll
        for (int h = 0; h < 8; ++h) c += tanhf(w_sh[h] + u_lds[n * H + h]) * vw[h];
        a_lds[n] = 1.f / (1.f + expf(-c));
    }
    __syncthreads();

    float acc = 0.f;
    #pragma unroll 4
    for (int n = 0; n < NCL; ++n) acc += a_lds[n] * m[n * EMB + tid];
    out[bs * EMB + tid] = acc;
}

extern "C" void kernel_launch(void* const* d_in, const int* in_sizes, int n_in,
                              void* d_out, int out_size, void* d_ws, size_t ws_size,
                              hipStream_t stream) {
    const float* x    = (const float*)d_in[0];
    const float* mask = (const float*)d_in[1];
    const float* W_w  = (const float*)d_in[2];
    const float* W_b  = (const float*)d_in[3];
    const float* U_w  = (const float*)d_in[4];
    const float* U_b  = (const float*)d_in[5];
    const float* v_w  = (const float*)d_in[6];
    const float* v_b  = (const float*)d_in[7];
    const float* m    = (const float*)d_in[8];
    float* out = (float*)d_out;

    float* ws     = (float*)d_ws;
    float* pooled = ws;                       // B*S*FEA floats
    float* w_buf  = ws + B * S * FEA;
    float* u_buf  = w_buf + B * S * H;

    pool_mfma_kernel<<<dim3(FEA / 64, B), 256, 0, stream>>>(x, mask, pooled);
    wu_kernel<<<B * S + NCL / 64, 256, 0, stream>>>(
        pooled, mask, W_w, W_b, U_w, U_b, m, w_buf, u_buf);
    attn_kernel<<<B * S, 256, 0, stream>>>(w_buf, u_buf, v_w, v_b, m, out);
}